// Round 8
// baseline (395.001 us; speedup 1.0000x reference)
//
#include <hip/hip_runtime.h>
#include <hip/hip_bf16.h>
#include <stdint.h>

// ERGCNConv on MI355X (gfx950).
// R10: merge agg_k + node_gemm_k into na_k (block = 32 nodes of one ntype):
//      GEMM (16 MFMA/wave, per-ks B loads) -> agg gather phase (R0 body, 8 dsts/wave,
//      results to LDS aggbuf) -> fused epilogue relu(gemm + agg + b_node).
//      Mechanism: agg's latency-bound gathers co-schedule with other waves' MFMA
//      (m114); -51 MB traffic (no global agg buffer); -1 launch.
//      hw_gemm/prep/hist/scatter: R9 verbatim (bitmap-predicated stores kept).
// Pipeline: memset | prep | hist(+bitmap) | scan1/2/3 | scatter
//           | hw_gemm (predicated stores) | na_k (agg+node fused)

#define D 128
#define TRELS 16
#define NTYPES 8

typedef __bf16 bf16x8 __attribute__((ext_vector_type(8)));
typedef float f32x4 __attribute__((ext_vector_type(4)));
typedef unsigned int u32x4 __attribute__((ext_vector_type(4)));

__device__ __forceinline__ unsigned short f2bf(float f) {
  union { float f; unsigned u; } v; v.f = f;
  unsigned u = v.u;
  return (unsigned short)((u + 0x7FFFu + ((u >> 16) & 1u)) >> 16);  // RNE
}
__device__ __forceinline__ float bf2f(unsigned short h) {
  union { unsigned u; float f; } v; v.u = ((unsigned)h) << 16;
  return v.f;
}

// ---------- prep: feats -> bf16; W_edge/W_node -> transposed bf16 [t][n][k] ----------
__global__ void prep_k(const float* __restrict__ feats,
                       const float* __restrict__ We,
                       const float* __restrict__ Wn,
                       unsigned short* __restrict__ featsbf,
                       unsigned short* __restrict__ WeT,
                       unsigned short* __restrict__ WnT,
                       int nfeat) {
  int idx = blockIdx.x * 256 + threadIdx.x;
  if (idx < nfeat) { featsbf[idx] = f2bf(feats[idx]); return; }
  idx -= nfeat;
  if (idx < TRELS * D * D) {
    int t = idx >> 14, rem = idx & 16383;
    int n = rem >> 7, k = rem & 127;
    WeT[idx] = f2bf(We[t * 16384 + k * 128 + n]);   // B^T layout: [n][k]
    return;
  }
  idx -= TRELS * D * D;
  if (idx < NTYPES * D * D) {
    int t = idx >> 14, rem = idx & 16383;
    int n = rem >> 7, k = rem & 127;
    WnT[idx] = f2bf(Wn[t * 16384 + k * 128 + n]);
  }
}

// ---------- hist: cnt[dst*16+et]++, node-type histogram, used-(src,et) bitmap ----------
__global__ void hist_k(const int* __restrict__ src, const int* __restrict__ dst,
                       const int* __restrict__ etypes,
                       const int* __restrict__ ntypes, int E, int N,
                       int* __restrict__ cnt, int* __restrict__ nhist,
                       int* __restrict__ srcuse) {
  __shared__ int sh_n[NTYPES];
  int tid = threadIdx.x;
  if (tid < NTYPES) sh_n[tid] = 0;
  __syncthreads();
  int g = blockIdx.x * 256 + tid;
  if (g < E) {
    int et = etypes[g];
    atomicAdd(&cnt[dst[g] * TRELS + et], 1);
    atomicOr(&srcuse[src[g]], 1 << et);
  }
  if (g < N) atomicAdd(&sh_n[ntypes[g]], 1);
  __syncthreads();
  if (tid < NTYPES && sh_n[tid]) atomicAdd(&nhist[tid], sh_n[tid]);
}

// misc layout (ints): noff[0..8], ntb[9..17], ncur[18..25], nhist[26..33], bsum[64..127]
// ---------- scan1: deg from cnt rows; block-local exclusive scan -> doff; block sums ----------
__global__ void scan1_k(const int* __restrict__ cnt, int* __restrict__ doff,
                        int* __restrict__ bsum, int N) {
  __shared__ int sd[256];
  int b = blockIdx.x, tid = threadIdx.x;
  int base = b * 1024 + tid * 4;
  int v[4]; int tot = 0;
  for (int j = 0; j < 4; ++j) {
    int i = base + j;
    int dg = 0;
    if (i < N) {
      const int* row = cnt + i * TRELS;
#pragma unroll
      for (int et = 0; et < TRELS; ++et) dg += row[et];
    }
    v[j] = tot; tot += dg;
  }
  sd[tid] = tot;
  __syncthreads();
  for (int off = 1; off < 256; off <<= 1) {
    int t = (tid >= off) ? sd[tid - off] : 0;
    __syncthreads();
    sd[tid] += t;
    __syncthreads();
  }
  int excl = sd[tid] - tot;
  for (int j = 0; j < 4; ++j) {
    int i = base + j;
    if (i < N) doff[i] = excl + v[j];
  }
  if (tid == 255) bsum[b] = sd[255];
}

// ---------- scan2: scan block sums; node-type scan (32-node tile granularity) ----------
__global__ void scan2_k(int* __restrict__ misc, int* __restrict__ bsum, int nb) {
  if (threadIdx.x != 0) return;
  int run = 0;
  for (int b = 0; b < nb; ++b) { int t = bsum[b]; bsum[b] = run; run += t; }
  int* noff = misc; int* ntb = misc + 9; int* ncur = misc + 18; int* nhist = misc + 26;
  int s = 0, ts = 0;
  for (int t = 0; t < NTYPES; ++t) {
    noff[t] = s; ncur[t] = s; ntb[t] = ts;
    s += nhist[t]; ts += (nhist[t] + 31) >> 5;
  }
  noff[NTYPES] = s; ntb[NTYPES] = ts;
}

// ---------- scan3: add block offsets; init dcur; doff[N] = E ----------
__global__ void scan3_k(int* __restrict__ doff, int* __restrict__ dcur,
                        const int* __restrict__ bsum, int N, int E) {
  int b = blockIdx.x, tid = threadIdx.x;
  int add = bsum[b];
  int base = b * 1024 + tid * 4;
  for (int j = 0; j < 4; ++j) {
    int i = base + j;
    if (i < N) { int o = doff[i] + add; doff[i] = o; dcur[i] = o; }
  }
  if (b == 0 && tid == 0) doff[N] = E;
}

// ---------- scatter: edges -> dst-sorted packed keys; nodes -> ntype-sorted ----------
__global__ void scatter_k(const int* __restrict__ src, const int* __restrict__ dst,
                          const int* __restrict__ etypes, const int* __restrict__ ntypes,
                          int E, int N, int* __restrict__ misc,
                          int* __restrict__ dcur,
                          int* __restrict__ edst, int* __restrict__ nsorted) {
  __shared__ int lc_n[NTYPES], lb_n[NTYPES];
  int tid = threadIdx.x;
  if (tid < NTYPES) lc_n[tid] = 0;
  __syncthreads();
  int g = blockIdx.x * 256 + tid;
  if (g < E) {
    int d = dst[g];
    int pos = atomicAdd(&dcur[d], 1);
    edst[pos] = src[g] * TRELS + etypes[g];   // packed key
  }
  int tn = -1, idn = 0;
  if (g < N) { tn = ntypes[g]; idn = atomicAdd(&lc_n[tn], 1); }
  __syncthreads();
  if (tid < NTYPES && lc_n[tid]) lb_n[tid] = atomicAdd(&misc[18 + tid], lc_n[tid]);
  __syncthreads();
  if (g < N) nsorted[lb_n[tn] + idn] = g;
}

// ---------- hW GEMM: hW[et] = feats @ W_et (bf16 out) — R9 verbatim ----------
__global__ __launch_bounds__(256) void hw_gemm_k(
    const unsigned short* __restrict__ featsbf,
    const unsigned short* __restrict__ WeT,
    const int* __restrict__ srcuse,
    unsigned short* __restrict__ hW, int N, int mtiles) {
  __shared__ unsigned char Asm[128 * 264];
  __shared__ unsigned char sm_use[128];
  int tid = threadIdx.x;

  int G = mtiles * 16;
  int q = G >> 3, rmod = G & 7;
  int xcd = blockIdx.x & 7, bidx = blockIdx.x >> 3;
  int wrk = (xcd < rmod) ? (xcd * (q + 1) + bidx)
                         : (rmod * (q + 1) + (xcd - rmod) * q + bidx);
  int tile = wrk >> 4;
  int et = wrk & 15;

  int lane = tid & 63, w = tid >> 6;
  int m = lane & 15, qd = lane >> 4;
  int rw = (w & 1) * 64, cw = (w >> 1) * 64;

  const unsigned short* WB = WeT + (size_t)et * (D * D);
  bf16x8 bfr[4][4];
#pragma unroll
  for (int ks = 0; ks < 4; ++ks)
#pragma unroll
    for (int j = 0; j < 4; ++j)
      bfr[ks][j] = *reinterpret_cast<const bf16x8*>(WB + (cw + j * 16 + m) * D + ks * 32 + qd * 8);

  if (tid < 128) {
    int rowu = tile * 128 + tid;
    sm_use[tid] = (rowu < N) ? (unsigned char)((srcuse[rowu] >> et) & 1) : 0;
  }

  int r = tid >> 1, h = tid & 1;
  int row = tile * 128 + r;
  if (row < N) {
    const u32x4* gp = reinterpret_cast<const u32x4*>(featsbf + (size_t)row * D);
#pragma unroll
    for (int cc = 0; cc < 8; ++cc) {
      int c = h * 8 + cc;
      *reinterpret_cast<u32x4*>(&Asm[r * 256 + ((c ^ (r & 7)) << 4)]) = gp[c];
    }
  }
  __syncthreads();

  f32x4 acc[4][4];
#pragma unroll
  for (int i = 0; i < 4; ++i)
#pragma unroll
    for (int j = 0; j < 4; ++j) acc[i][j] = (f32x4){0.f, 0.f, 0.f, 0.f};

#pragma unroll
  for (int ks = 0; ks < 4; ++ks) {
    bf16x8 a[4];
#pragma unroll
    for (int i = 0; i < 4; ++i) {
      int rr = rw + i * 16 + m;
      int c = ks * 4 + qd;
      a[i] = *reinterpret_cast<const bf16x8*>(&Asm[rr * 256 + ((c ^ (rr & 7)) << 4)]);
    }
#pragma unroll
    for (int i = 0; i < 4; ++i)
#pragma unroll
      for (int j = 0; j < 4; ++j)
        acc[i][j] = __builtin_amdgcn_mfma_f32_16x16x32_bf16(a[i], bfr[ks][j], acc[i][j], 0, 0, 0);
  }

  __syncthreads();
  unsigned short* Cs = reinterpret_cast<unsigned short*>(Asm);
#pragma unroll
  for (int i = 0; i < 4; ++i)
#pragma unroll
    for (int j = 0; j < 4; ++j)
#pragma unroll
      for (int reg = 0; reg < 4; ++reg) {
        int rr = rw + i * 16 + qd * 4 + reg;  // C/D: row = quad*4+reg, col = m
        Cs[rr * 132 + cw + j * 16 + m] = f2bf(acc[i][j][reg]);
      }
  __syncthreads();
  char* gout = (char*)(hW + ((size_t)et * N + (size_t)tile * 128) * D);
#pragma unroll
  for (int cp = 0; cp < 8; ++cp) {
    int o = cp * 4096 + tid * 16;     // byte offset in logical 128x256B tile
    int rloc = o >> 8;
    if (tile * 128 + rloc < N && sm_use[rloc]) {
      u32x4 v = *reinterpret_cast<const u32x4*>(&Asm[rloc * 264 + (o & 255)]);
      *reinterpret_cast<u32x4*>(gout + o) = v;
    }
  }
}

// ---------- na: fused node-GEMM + agg. Block = 32 nodes of one ntype ----------
// Waves as 2x2: wave w -> rows (w>>1)*16, cols (w&1)*64 of the 32x128 GEMM tile.
// Phase 1: GEMM (B per-ks, 16 MFMA/wave, acc[4]). Phase 2: agg gathers (R0 body,
// 8 dsts/wave, + edge-bias) into LDS aggbuf. Phase 3: epilogue relu(C+agg+b_node).
__global__ __launch_bounds__(256) void na_k(
    const unsigned short* __restrict__ featsbf,
    const unsigned short* __restrict__ WnT,
    const float* __restrict__ b_node,
    const float* __restrict__ b_edge,
    const unsigned short* __restrict__ hW,
    const int* __restrict__ cnt,
    const int* __restrict__ doff, const int* __restrict__ edst,
    const int* __restrict__ nsorted, const int* __restrict__ misc,
    float* __restrict__ out, int N) {
  __shared__ unsigned char Asm[32 * 264];     // 8.25 KB A-tile; reused as 16x528B Cf
  __shared__ float aggbuf[32][128];           // 16 KB
  __shared__ int sm_node[32];
  __shared__ int s_ntb[9];
  int tid = threadIdx.x;
  if (tid < 9) s_ntb[tid] = misc[9 + tid];
  __syncthreads();
  int bid = blockIdx.x;
  if (bid >= s_ntb[8]) return;
  int t = 0;
  while (bid >= s_ntb[t + 1]) ++t;
  int tile = bid - s_ntb[t];
  int noff_t = misc[t];
  int cntT = misc[t + 1] - noff_t;

  int lane = tid & 63, w = tid >> 6;
  int m = lane & 15, q = lane >> 4;
  int wr = w >> 1, wc = w & 1;

  if (tid < 32) {
    int gidx = tile * 32 + tid;
    sm_node[tid] = (gidx < cntT) ? nsorted[noff_t + gidx] : -1;
  }
  __syncthreads();

  // stage A: 32 rows x 256 B, 8 threads/row x 2 x 16 B, xor-swizzled
  {
    int r = tid >> 3, h = tid & 7;
    int node = sm_node[r];
    if (node >= 0) {
      const u32x4* gp = reinterpret_cast<const u32x4*>(featsbf + (size_t)node * D);
#pragma unroll
      for (int cc = 0; cc < 2; ++cc) {
        int c = h * 2 + cc;
        *reinterpret_cast<u32x4*>(&Asm[r * 256 + ((c ^ (r & 7)) << 4)]) = gp[c];
      }
    }
  }
  __syncthreads();

  // GEMM: wave computes 16x64; B frags loaded per-ks (keeps VGPR low)
  const unsigned short* WB = WnT + (size_t)t * (D * D);
  f32x4 acc[4];
#pragma unroll
  for (int j = 0; j < 4; ++j) acc[j] = (f32x4){0.f, 0.f, 0.f, 0.f};
#pragma unroll
  for (int ks = 0; ks < 4; ++ks) {
    bf16x8 bfr[4];
#pragma unroll
    for (int j = 0; j < 4; ++j)
      bfr[j] = *reinterpret_cast<const bf16x8*>(WB + (wc * 64 + j * 16 + m) * D + ks * 32 + q * 8);
    int rr = wr * 16 + m;
    int c = ks * 4 + q;
    bf16x8 a = *reinterpret_cast<const bf16x8*>(&Asm[rr * 256 + ((c ^ (rr & 7)) << 4)]);
#pragma unroll
    for (int j = 0; j < 4; ++j)
      acc[j] = __builtin_amdgcn_mfma_f32_16x16x32_bf16(a, bfr[j], acc[j], 0, 0, 0);
  }

  // agg phase: wave w handles dsts w*8 .. w*8+7 (R0 agg body per dst)
  for (int widx = 0; widx < 8; ++widx) {
    int dloc = w * 8 + widx;
    int d = sm_node[dloc];
    if (d < 0) continue;
    int cv = 0;
    if (lane < TRELS) cv = cnt[d * TRELS + lane];
    float invl = (cv > 0) ? 1.0f / (float)cv : 0.0f;
    int start = doff[d], end = doff[d + 1];
    float ax = 0.f, ay = 0.f;
    for (int base = start; base < end; base += 64) {
      int key = 0;
      if (base + lane < end) key = edst[base + lane];
      int nchunk = end - base; if (nchunk > 64) nchunk = 64;
      int j = 0;
      for (; j + 4 <= nchunk; j += 4) {
        int k0 = __shfl(key, j, 64), k1 = __shfl(key, j + 1, 64);
        int k2 = __shfl(key, j + 2, 64), k3 = __shfl(key, j + 3, 64);
        float i0 = __shfl(invl, k0 & 15, 64), i1 = __shfl(invl, k1 & 15, 64);
        float i2 = __shfl(invl, k2 & 15, 64), i3 = __shfl(invl, k3 & 15, 64);
        ushort2 h0 = *reinterpret_cast<const ushort2*>(hW + ((size_t)(k0 & 15) * N + (k0 >> 4)) * D + lane * 2);
        ushort2 h1 = *reinterpret_cast<const ushort2*>(hW + ((size_t)(k1 & 15) * N + (k1 >> 4)) * D + lane * 2);
        ushort2 h2 = *reinterpret_cast<const ushort2*>(hW + ((size_t)(k2 & 15) * N + (k2 >> 4)) * D + lane * 2);
        ushort2 h3 = *reinterpret_cast<const ushort2*>(hW + ((size_t)(k3 & 15) * N + (k3 >> 4)) * D + lane * 2);
        ax += i0 * bf2f(h0.x); ay += i0 * bf2f(h0.y);
        ax += i1 * bf2f(h1.x); ay += i1 * bf2f(h1.y);
        ax += i2 * bf2f(h2.x); ay += i2 * bf2f(h2.y);
        ax += i3 * bf2f(h3.x); ay += i3 * bf2f(h3.y);
      }
      for (; j < nchunk; ++j) {
        int k = __shfl(key, j, 64);
        float inv = __shfl(invl, k & 15, 64);
        ushort2 hv = *reinterpret_cast<const ushort2*>(hW + ((size_t)(k & 15) * N + (k >> 4)) * D + lane * 2);
        ax += inv * bf2f(hv.x); ay += inv * bf2f(hv.y);
      }
    }
#pragma unroll
    for (int et = 0; et < TRELS; ++et) {
      int c2 = __shfl(cv, et, 64);
      if (c2 > 0) {
        const float* bp = b_edge + et * D + lane * 2;
        ax += bp[0]; ay += bp[1];
      }
    }
    aggbuf[dloc][lane * 2] = ax;
    aggbuf[dloc][lane * 2 + 1] = ay;
  }
  __syncthreads();   // aggbuf ready; A-tile dead -> Asm reusable as Cf

  // epilogue: 2 halves x 16 rows through Cf (= Asm), fused agg + b_node + relu
  const float* bnp = b_node + t * D;
  float* Cf = reinterpret_cast<float*>(Asm);
#pragma unroll
  for (int half = 0; half < 2; ++half) {
    if (wr == half) {
#pragma unroll
      for (int j = 0; j < 4; ++j)
#pragma unroll
        for (int reg = 0; reg < 4; ++reg) {
          int rl = q * 4 + reg;          // 0..15
          Cf[rl * 132 + wc * 64 + j * 16 + m] = acc[j][reg];
        }
    }
    __syncthreads();
#pragma unroll
    for (int cp = 0; cp < 2; ++cp) {
      int o = cp * 4096 + tid * 16;     // 16 rows x 512 B half tile
      int rl = o >> 9;
      int dl = half * 16 + rl;
      int nd = sm_node[dl];
      if (nd >= 0) {
        int col = (o & 511) >> 2;
        f32x4 c = *reinterpret_cast<const f32x4*>((char*)Cf + rl * 528 + (o & 511));
        f32x4 a = *reinterpret_cast<const f32x4*>(&aggbuf[dl][col]);
        f32x4 b4 = *reinterpret_cast<const f32x4*>(bnp + col);
        f32x4 res;
#pragma unroll
        for (int z = 0; z < 4; ++z) res[z] = fmaxf(c[z] + a[z] + b4[z], 0.f);
        *reinterpret_cast<f32x4*>(out + (size_t)nd * D + col) = res;
      }
    }
    __syncthreads();
  }
}

static inline size_t align256(size_t x) { return (x + 255) & ~(size_t)255; }

extern "C" void kernel_launch(void* const* d_in, const int* in_sizes, int n_in,
                              void* d_out, int out_size, void* d_ws, size_t ws_size,
                              hipStream_t stream) {
  const float* feats  = (const float*)d_in[0];
  const float* W_edge = (const float*)d_in[1];
  const float* b_edge = (const float*)d_in[2];
  const float* W_node = (const float*)d_in[3];
  const float* b_node = (const float*)d_in[4];
  const int* src    = (const int*)d_in[5];
  const int* dst    = (const int*)d_in[6];
  const int* ntypes = (const int*)d_in[7];
  const int* etypes = (const int*)d_in[8];
  int N = in_sizes[0] / D;   // 50000
  int E = in_sizes[5];       // 640000

  char* ws = (char*)d_ws;
  size_t o_cnt  = 0;
  size_t o_misc = align256(o_cnt + (size_t)N * TRELS * 4);
  size_t o_su   = align256(o_misc + 512);
  size_t zend   = align256(o_su + (size_t)N * 4);
  size_t o_doff = zend;
  size_t o_dcur = align256(o_doff + (size_t)(N + 1) * 4);
  size_t o_edst = align256(o_dcur + (size_t)N * 4);
  size_t o_ns   = align256(o_edst + (size_t)E * 4);
  size_t o_fb   = align256(o_ns + (size_t)N * 4);
  size_t o_we   = align256(o_fb + (size_t)N * D * 2);
  size_t o_wn   = align256(o_we + (size_t)TRELS * D * D * 2);
  size_t o_hw   = align256(o_wn + (size_t)NTYPES * D * D * 2);

  int* cnt = (int*)(ws + o_cnt);
  int* misc = (int*)(ws + o_misc);
  int* srcuse = (int*)(ws + o_su);
  int* doff = (int*)(ws + o_doff);
  int* dcur = (int*)(ws + o_dcur);
  int* edst = (int*)(ws + o_edst);
  int* nsorted = (int*)(ws + o_ns);
  unsigned short* featsbf = (unsigned short*)(ws + o_fb);
  unsigned short* WeT = (unsigned short*)(ws + o_we);
  unsigned short* WnT = (unsigned short*)(ws + o_wn);
  unsigned short* hW = (unsigned short*)(ws + o_hw);
  int* bsum = misc + 64;

  (void)hipMemsetAsync(ws, 0, zend, stream);

  int nfeat = N * D;
  int ptot = nfeat + TRELS * D * D + NTYPES * D * D;
  prep_k<<<(ptot + 255) / 256, 256, 0, stream>>>(feats, W_edge, W_node, featsbf, WeT, WnT, nfeat);

  int hgrid = ((E > N ? E : N) + 255) / 256;
  hist_k<<<hgrid, 256, 0, stream>>>(src, dst, etypes, ntypes, E, N, cnt, misc + 26, srcuse);

  int nb = (N + 1023) / 1024;
  scan1_k<<<nb, 256, 0, stream>>>(cnt, doff, bsum, N);
  scan2_k<<<1, 64, 0, stream>>>(misc, bsum, nb);
  scan3_k<<<nb, 256, 0, stream>>>(doff, dcur, bsum, N, E);

  scatter_k<<<hgrid, 256, 0, stream>>>(src, dst, etypes, ntypes, E, N, misc, dcur, edst, nsorted);

  int mtiles = (N + 127) / 128;
  hw_gemm_k<<<mtiles * 16, 256, 0, stream>>>(featsbf, WeT, srcuse, hW, N, mtiles);

  int ngrid = (N + 31) / 32 + NTYPES;
  na_k<<<ngrid, 256, 0, stream>>>(featsbf, WnT, b_node, b_edge, hW, cnt, doff, edst,
                                  nsorted, misc, (float*)d_out, N);
}